// Round 5
// baseline (452.102 us; speedup 1.0000x reference)
//
#include <hip/hip_runtime.h>
#include <hip/hip_bf16.h>
#include <math.h>

#define BB 4
#define TT 2048
#define DD 1024
#define DLb 128
#define EE 8
#define HH 4
#define KK 3
#define HDh 32
#define NN (BB*TT)
#define NPOS 9
#define NCH 16
#define CHL (TT/NCH)
#define SEQSTR (NPOS*DLb)   // 1152
#define NSLICE 4
#define TSL (NN/NSLICE)     // 2048 tokens per slice
#define RSA 40

typedef __attribute__((ext_vector_type(8))) short short8;
typedef __attribute__((ext_vector_type(4))) float f32x4;
typedef __attribute__((ext_vector_type(8))) unsigned short ushort8;
typedef __attribute__((ext_vector_type(4))) unsigned short ushort4v;

__device__ __forceinline__ float gelu_exact(float v) {
    return 0.5f * v * (1.0f + erff(v * 0.70710678118654752440f));
}

__device__ __forceinline__ unsigned short f2bf(float x) {
    __hip_bfloat16 h = __float2bfloat16(x);
    return *reinterpret_cast<unsigned short*>(&h);
}

__device__ __forceinline__ float bf2f(unsigned short u) {
    return __uint_as_float(((unsigned int)u) << 16);
}

__device__ __forceinline__ float4 rec4(const unsigned short* h, const unsigned short* l) {
    ushort4v hv = *(const ushort4v*)h;
    ushort4v lv = *(const ushort4v*)l;
    float4 r;
    r.x = bf2f(hv[0]) + bf2f(lv[0]);
    r.y = bf2f(hv[1]) + bf2f(lv[1]);
    r.z = bf2f(hv[2]) + bf2f(lv[2]);
    r.w = bf2f(hv[3]) + bf2f(lv[3]);
    return r;
}

// ---------------- K0: generic fp32 -> (hi,lo) bf16 split ----------------
__global__ __launch_bounds__(256) void ksplit(const float* __restrict__ src,
                                              unsigned short* __restrict__ h,
                                              unsigned short* __restrict__ l, int n8)
{
    int i = blockIdx.x * 256 + threadIdx.x;
    if (i >= n8) return;
    size_t g = (size_t)i * 8;
    float4 a = *(const float4*)&src[g];
    float4 b = *(const float4*)&src[g + 4];
    float vv[8] = {a.x, a.y, a.z, a.w, b.x, b.y, b.z, b.w};
    ushort8 ho, lo;
    #pragma unroll
    for (int j = 0; j < 8; j++) {
        unsigned short hh = f2bf(vv[j]);
        float hf = bf2f(hh);
        ho[j] = hh;
        lo[j] = f2bf(vv[j] - hf);
    }
    *(ushort8*)&h[g] = ho;
    *(ushort8*)&l[g] = lo;
}

// ---------------- K1: per-batch column mean of x ----------------
__global__ __launch_bounds__(256) void k1a(const float* __restrict__ x, float* __restrict__ partial) {
    int d = blockIdx.x * 256 + threadIdx.x;
    int b = blockIdx.y, c = blockIdx.z;
    const float* xp = x + ((size_t)b * TT + (size_t)c * CHL) * DD + d;
    float s = 0.0f;
    for (int t = 0; t < CHL; t++) s += xp[(size_t)t * DD];
    partial[(b * NCH + c) * DD + d] = s;
}

__global__ __launch_bounds__(256) void k1b(const float* __restrict__ partial, float* __restrict__ mean_x) {
    int d = blockIdx.x * 256 + threadIdx.x;
    int b = blockIdx.y;
    float s = 0.0f;
    for (int c = 0; c < NCH; c++) s += partial[(b * NCH + c) * DD + d];
    mean_x[b * DD + d] = s * (1.0f / TT);
}

// ---------------- K2: per-batch gctx + rq chain ----------------
__global__ __launch_bounds__(128) void k2_batch(
    const float* __restrict__ mean_x,
    const float* __restrict__ gpw, const float* __restrict__ gpb,
    const float* __restrict__ rq1w, const float* __restrict__ rq1b,
    const float* __restrict__ lnw, const float* __restrict__ lnb,
    const float* __restrict__ rq2w, const float* __restrict__ rq2b,
    float* __restrict__ gctx, float* __restrict__ rqv)
{
    int b = blockIdx.x, d = threadIdx.x;
    __shared__ __attribute__((aligned(16))) float g[DLb];
    __shared__ __attribute__((aligned(16))) float t1[DLb];
    __shared__ __attribute__((aligned(16))) float act[DLb];
    __shared__ float red[2];
    {
        const float4* wrow = (const float4*)(gpw + (size_t)d * DD);
        const float4* mx4  = (const float4*)(mean_x + (size_t)b * DD);
        float s = gpb[d];
        for (int k = 0; k < DD / 4; k++) {
            float4 w = wrow[k], m = mx4[k];
            s += w.x * m.x + w.y * m.y + w.z * m.z + w.w * m.w;
        }
        g[d] = s;
        gctx[b * DLb + d] = s;
    }
    __syncthreads();
    {
        float s = rq1b[d];
        for (int k = 0; k < DLb; k++) s += g[k] * rq1w[d * DLb + k];
        t1[d] = s;
    }
    __syncthreads();
    if (d == 0) {
        float m = 0.0f;
        for (int i = 0; i < DLb; i++) m += t1[i];
        m *= (1.0f / DLb);
        float v = 0.0f;
        for (int i = 0; i < DLb; i++) { float df = t1[i] - m; v += df * df; }
        v *= (1.0f / DLb);
        red[0] = m; red[1] = 1.0f / sqrtf(v + 1e-5f);
    }
    __syncthreads();
    {
        float xn = (t1[d] - red[0]) * red[1] * lnw[d] + lnb[d];
        act[d] = gelu_exact(xn);
    }
    __syncthreads();
    {
        float s = rq2b[d];
        for (int k = 0; k < DLb; k++) s += act[k] * rq2w[d * DLb + k];
        rqv[b * DLb + d] = s;
    }
}

// ---------------- K2b: fill seq position 0 with gctx (split) ----------------
__global__ __launch_bounds__(256) void k2b(const float* __restrict__ gctx,
                                           unsigned short* __restrict__ seqh,
                                           unsigned short* __restrict__ seql) {
    int i = blockIdx.x * 256 + threadIdx.x;
    int n = i >> 7, d = i & 127;
    float v = gctx[(n >> 11) * DLb + d];
    unsigned short h = f2bf(v);
    seqh[(size_t)n * SEQSTR + d] = h;
    seql[(size_t)n * SEQSTR + d] = f2bf(v - bf2f(h));
}

// ---------------- K3s: seq[:,1:,:] = x @ w_down^T + pe (pure split-bf16 MFMA) ----------------
__global__ __launch_bounds__(256) void k3s(const unsigned short* __restrict__ XH,
                                           const unsigned short* __restrict__ XL,
                                           const unsigned short* __restrict__ WH,
                                           const unsigned short* __restrict__ WL,
                                           const float* __restrict__ pe,
                                           unsigned short* __restrict__ seqh,
                                           unsigned short* __restrict__ seql)
{
    __shared__ __attribute__((aligned(16))) unsigned short Ah[128 * RSA];
    __shared__ __attribute__((aligned(16))) unsigned short Al[128 * RSA];
    __shared__ __attribute__((aligned(16))) unsigned short Bh[128 * RSA];
    __shared__ __attribute__((aligned(16))) unsigned short Bl[128 * RSA];
    int tid = threadIdx.x;
    int lane = tid & 63, wave = tid >> 6;
    int wm = wave & 1, wn = wave >> 1;
    int row0 = blockIdx.y * 128, col0 = blockIdx.x * 128;
    int fr = lane & 15, fq = lane >> 4;
    f32x4 acc[4][4];
    #pragma unroll
    for (int i = 0; i < 4; i++)
        #pragma unroll
        for (int j = 0; j < 4; j++) acc[i][j] = (f32x4)0.0f;

    for (int k0 = 0; k0 < DD; k0 += 32) {
        #pragma unroll
        for (int i = 0; i < 2; i++) {
            int L = i * 256 + tid;
            int r = L >> 2, q = (L & 3) * 8;
            *(ushort8*)&Ah[r * RSA + q] = *(const ushort8*)&XH[(size_t)(row0 + r) * DD + k0 + q];
            *(ushort8*)&Al[r * RSA + q] = *(const ushort8*)&XL[(size_t)(row0 + r) * DD + k0 + q];
            *(ushort8*)&Bh[r * RSA + q] = *(const ushort8*)&WH[(size_t)(col0 + r) * DD + k0 + q];
            *(ushort8*)&Bl[r * RSA + q] = *(const ushort8*)&WL[(size_t)(col0 + r) * DD + k0 + q];
        }
        __syncthreads();
        short8 ah[4], al4[4], bh[4], bl4[4];
        #pragma unroll
        for (int f = 0; f < 4; f++) {
            int ra = (wm * 64 + f * 16 + fr) * RSA + fq * 8;
            int rb = (wn * 64 + f * 16 + fr) * RSA + fq * 8;
            ah[f]  = *(const short8*)&Ah[ra];
            al4[f] = *(const short8*)&Al[ra];
            bh[f]  = *(const short8*)&Bh[rb];
            bl4[f] = *(const short8*)&Bl[rb];
        }
        #pragma unroll
        for (int i = 0; i < 4; i++)
            #pragma unroll
            for (int j = 0; j < 4; j++) {
                acc[i][j] = __builtin_amdgcn_mfma_f32_16x16x32_bf16(ah[i],  bh[j],  acc[i][j], 0, 0, 0);
                acc[i][j] = __builtin_amdgcn_mfma_f32_16x16x32_bf16(ah[i],  bl4[j], acc[i][j], 0, 0, 0);
                acc[i][j] = __builtin_amdgcn_mfma_f32_16x16x32_bf16(al4[i], bh[j],  acc[i][j], 0, 0, 0);
            }
        __syncthreads();
    }
    #pragma unroll
    for (int j = 0; j < 4; j++) {
        int gc = col0 + wn * 64 + j * 16 + fr;
        float pv = pe[gc];
        #pragma unroll
        for (int i = 0; i < 4; i++) {
            #pragma unroll
            for (int r = 0; r < 4; r++) {
                int gr = row0 + wm * 64 + i * 16 + fq * 4 + r;
                float v = acc[i][j][r] + pv;
                unsigned short h = f2bf(v);
                size_t idx = (size_t)gr * SEQSTR + DLb + gc;
                seqh[idx] = h;
                seql[idx] = f2bf(v - bf2f(h));
            }
        }
    }
}

// ---------------- K4as: qkv slice GEMM (pure split-bf16 MFMA) ----------------
// A: (TSL*9,128) slice of seq (hi/lo); W: (384,128) hi/lo; C: (TSL*9,384) fp32
__global__ __launch_bounds__(256) void k4as(const unsigned short* __restrict__ AHp,
                                            const unsigned short* __restrict__ ALp,
                                            const unsigned short* __restrict__ WHp,
                                            const unsigned short* __restrict__ WLp,
                                            const float* __restrict__ bias,
                                            float* __restrict__ C)
{
    __shared__ __attribute__((aligned(16))) unsigned short Ah[128 * RSA];
    __shared__ __attribute__((aligned(16))) unsigned short Al[128 * RSA];
    __shared__ __attribute__((aligned(16))) unsigned short Bh[128 * RSA];
    __shared__ __attribute__((aligned(16))) unsigned short Bl[128 * RSA];
    int tid = threadIdx.x;
    int lane = tid & 63, wave = tid >> 6;
    int wm = wave & 1, wn = wave >> 1;
    int row0 = blockIdx.y * 128, col0 = blockIdx.x * 128;
    int fr = lane & 15, fq = lane >> 4;
    f32x4 acc[4][4];
    #pragma unroll
    for (int i = 0; i < 4; i++)
        #pragma unroll
        for (int j = 0; j < 4; j++) acc[i][j] = (f32x4)0.0f;

    for (int k0 = 0; k0 < DLb; k0 += 32) {
        #pragma unroll
        for (int i = 0; i < 2; i++) {
            int L = i * 256 + tid;
            int r = L >> 2, q = (L & 3) * 8;
            *(ushort8*)&Ah[r * RSA + q] = *(const ushort8*)&AHp[(size_t)(row0 + r) * DLb + k0 + q];
            *(ushort8*)&Al[r * RSA + q] = *(const ushort8*)&ALp[(size_t)(row0 + r) * DLb + k0 + q];
            *(ushort8*)&Bh[r * RSA + q] = *(const ushort8*)&WHp[(size_t)(col0 + r) * DLb + k0 + q];
            *(ushort8*)&Bl[r * RSA + q] = *(const ushort8*)&WLp[(size_t)(col0 + r) * DLb + k0 + q];
        }
        __syncthreads();
        short8 ah[4], al4[4], bh[4], bl4[4];
        #pragma unroll
        for (int f = 0; f < 4; f++) {
            int ra = (wm * 64 + f * 16 + fr) * RSA + fq * 8;
            int rb = (wn * 64 + f * 16 + fr) * RSA + fq * 8;
            ah[f]  = *(const short8*)&Ah[ra];
            al4[f] = *(const short8*)&Al[ra];
            bh[f]  = *(const short8*)&Bh[rb];
            bl4[f] = *(const short8*)&Bl[rb];
        }
        #pragma unroll
        for (int i = 0; i < 4; i++)
            #pragma unroll
            for (int j = 0; j < 4; j++) {
                acc[i][j] = __builtin_amdgcn_mfma_f32_16x16x32_bf16(ah[i],  bh[j],  acc[i][j], 0, 0, 0);
                acc[i][j] = __builtin_amdgcn_mfma_f32_16x16x32_bf16(ah[i],  bl4[j], acc[i][j], 0, 0, 0);
                acc[i][j] = __builtin_amdgcn_mfma_f32_16x16x32_bf16(al4[i], bh[j],  acc[i][j], 0, 0, 0);
            }
        __syncthreads();
    }
    #pragma unroll
    for (int j = 0; j < 4; j++) {
        int gc = col0 + wn * 64 + j * 16 + fr;
        float bv = bias[gc];
        #pragma unroll
        for (int i = 0; i < 4; i++) {
            #pragma unroll
            for (int r = 0; r < 4; r++) {
                int gr = row0 + wm * 64 + i * 16 + fq * 4 + r;
                C[(size_t)gr * 384 + gc] = acc[i][j][r] + bv;
            }
        }
    }
}

// ---------------- K4b: per-token attention (softmax + attn@v), pos 1..8 only ----------------
__global__ __launch_bounds__(256) void k4b(const float* __restrict__ qkv,
                                           float* __restrict__ og, int n0)
{
    int nl = blockIdx.x;
    int tid = threadIdx.x;
    __shared__ __attribute__((aligned(16))) float sq[NPOS][384];
    __shared__ float attnw[HH][NPOS][12];
    {
        const float4* src = (const float4*)(qkv + (size_t)nl * NPOS * 384);
        float4* dst = (float4*)&sq[0][0];
        for (int i = tid; i < NPOS * 384 / 4; i += 256) dst[i] = src[i];
    }
    __syncthreads();
    if (tid < HH * NPOS) {
        int h = tid / NPOS, i = tid % NPOS;
        float sc[NPOS];
        float mx = -1e30f;
        for (int j = 0; j < NPOS; j++) {
            float s = 0.0f;
            for (int d2 = 0; d2 < HDh; d2++)
                s += sq[i][h * HDh + d2] * sq[j][DLb + h * HDh + d2];
            s *= 0.17677669529663687f;
            sc[j] = s;
            mx = fmaxf(mx, s);
        }
        float se = 0.0f;
        for (int j = 0; j < NPOS; j++) { sc[j] = expf(sc[j] - mx); se += sc[j]; }
        float inv = 1.0f / se;
        for (int j = 0; j < NPOS; j++) attnw[h][i][j] = sc[j] * inv;
    }
    __syncthreads();
    #pragma unroll
    for (int it = 0; it < 4; it++) {
        int idx = it * 256 + tid;
        int p = 1 + (idx >> 7), d = idx & 127, h = d >> 5;
        float s = 0.0f;
        #pragma unroll
        for (int j = 0; j < NPOS; j++) s += attnw[h][p][j] * sq[j][2 * DLb + d];
        og[((size_t)(n0 + nl) * 8 + (p - 1)) * DLb + d] = s;
    }
}

// ---------------- K4c: s2 = LN(o @ aow^T + aob + residual) ----------------
__global__ __launch_bounds__(256) void k4c(const float* __restrict__ A,
                                           const float* __restrict__ W,
                                           const float* __restrict__ bias,
                                           const unsigned short* __restrict__ seqh,
                                           const unsigned short* __restrict__ seql,
                                           const float* __restrict__ nw,
                                           const float* __restrict__ nb,
                                           float* __restrict__ s2)
{
    __shared__ __attribute__((aligned(16))) float As[16][132];
    __shared__ __attribute__((aligned(16))) float Bs[16][132];
    __shared__ float redS[128][17];
    __shared__ float mstat[128][2];
    int tid = threadIdx.x;
    int tx = tid & 15, ty = tid >> 4;
    int row0 = blockIdx.y * 128;
    float acc[8][8] = {};
    for (int k0 = 0; k0 < DLb; k0 += 16) {
        #pragma unroll
        for (int i = 0; i < 2; i++) {
            int L = i * 256 + tid;
            int r = L >> 2, kq = (L & 3) * 4;
            float4 a4 = *(const float4*)&A[(size_t)(row0 + r) * DLb + k0 + kq];
            float4 b4 = *(const float4*)&W[(size_t)r * DLb + k0 + kq];
            As[kq + 0][r] = a4.x; As[kq + 1][r] = a4.y; As[kq + 2][r] = a4.z; As[kq + 3][r] = a4.w;
            Bs[kq + 0][r] = b4.x; Bs[kq + 1][r] = b4.y; Bs[kq + 2][r] = b4.z; Bs[kq + 3][r] = b4.w;
        }
        __syncthreads();
        #pragma unroll
        for (int kk = 0; kk < 16; kk++) {
            float4 a0 = *(const float4*)&As[kk][ty * 4];
            float4 a1 = *(const float4*)&As[kk][64 + ty * 4];
            float4 b0 = *(const float4*)&Bs[kk][tx * 4];
            float4 b1 = *(const float4*)&Bs[kk][64 + tx * 4];
            float ar[8] = {a0.x, a0.y, a0.z, a0.w, a1.x, a1.y, a1.z, a1.w};
            float bc[8] = {b0.x, b0.y, b0.z, b0.w, b1.x, b1.y, b1.z, b1.w};
            #pragma unroll
            for (int i = 0; i < 8; i++)
                #pragma unroll
                for (int j = 0; j < 8; j++)
                    acc[i][j] += ar[i] * bc[j];
        }
        __syncthreads();
    }
    float4 bb0 = *(const float4*)&bias[tx * 4];
    float4 bb1 = *(const float4*)&bias[64 + tx * 4];
    #pragma unroll
    for (int i = 0; i < 8; i++) {
        int rl = (i < 4) ? (ty * 4 + i) : (64 + ty * 4 + (i - 4));
        int m = row0 + rl;
        size_t roff = (size_t)(m >> 3) * SEQSTR + (size_t)((m & 7) + 1) * DLb;
        float4 r0 = rec4(&seqh[roff + tx * 4], &seql[roff + tx * 4]);
        float4 r1 = rec4(&seqh[roff + 64 + tx * 4], &seql[roff + 64 + tx * 4]);
        acc[i][0] += bb0.x + r0.x; acc[i][1] += bb0.y + r0.y;
        acc[i][2] += bb0.z + r0.z; acc[i][3] += bb0.w + r0.w;
        acc[i][4] += bb1.x + r1.x; acc[i][5] += bb1.y + r1.y;
        acc[i][6] += bb1.z + r1.z; acc[i][7] += bb1.w + r1.w;
        float ps = 0.0f;
        #pragma unroll
        for (int j = 0; j < 8; j++) ps += acc[i][j];
        redS[rl][tx] = ps;
    }
    __syncthreads();
    if (tid < 128) {
        float s = 0.0f;
        #pragma unroll
        for (int t = 0; t < 16; t++) s += redS[tid][t];
        mstat[tid][0] = s * (1.0f / DLb);
    }
    __syncthreads();
    #pragma unroll
    for (int i = 0; i < 8; i++) {
        int rl = (i < 4) ? (ty * 4 + i) : (64 + ty * 4 + (i - 4));
        float m = mstat[rl][0];
        float pv = 0.0f;
        #pragma unroll
        for (int j = 0; j < 8; j++) { float df = acc[i][j] - m; pv += df * df; }
        redS[rl][tx] = pv;
    }
    __syncthreads();
    if (tid < 128) {
        float s = 0.0f;
        #pragma unroll
        for (int t = 0; t < 16; t++) s += redS[tid][t];
        mstat[tid][1] = 1.0f / sqrtf(s * (1.0f / DLb) + 1e-5f);
    }
    __syncthreads();
    float4 nw0 = *(const float4*)&nw[tx * 4];
    float4 nw1 = *(const float4*)&nw[64 + tx * 4];
    float4 nb0 = *(const float4*)&nb[tx * 4];
    float4 nb1 = *(const float4*)&nb[64 + tx * 4];
    #pragma unroll
    for (int i = 0; i < 8; i++) {
        int rl = (i < 4) ? (ty * 4 + i) : (64 + ty * 4 + (i - 4));
        float m = mstat[rl][0], istd = mstat[rl][1];
        float* dst = s2 + (size_t)(row0 + rl) * DLb;
        float4 o0, o1;
        o0.x = (acc[i][0] - m) * istd * nw0.x + nb0.x;
        o0.y = (acc[i][1] - m) * istd * nw0.y + nb0.y;
        o0.z = (acc[i][2] - m) * istd * nw0.z + nb0.z;
        o0.w = (acc[i][3] - m) * istd * nw0.w + nb0.w;
        o1.x = (acc[i][4] - m) * istd * nw1.x + nb1.x;
        o1.y = (acc[i][5] - m) * istd * nw1.y + nb1.y;
        o1.z = (acc[i][6] - m) * istd * nw1.z + nb1.z;
        o1.w = (acc[i][7] - m) * istd * nw1.w + nb1.w;
        *(float4*)&dst[tx * 4] = o0;
        *(float4*)&dst[64 + tx * 4] = o1;
    }
}

// ---------------- K4d: rk GEMM + fused logits ----------------
__global__ __launch_bounds__(256) void k4d(const float* __restrict__ A,
                                           const float* __restrict__ W,
                                           const float* __restrict__ bias,
                                           const float* __restrict__ rqv,
                                           float* __restrict__ logits)
{
    __shared__ __attribute__((aligned(16))) float As[16][132];
    __shared__ __attribute__((aligned(16))) float Bs[16][132];
    __shared__ float redS[128][17];
    int tid = threadIdx.x;
    int tx = tid & 15, ty = tid >> 4;
    int row0 = blockIdx.y * 128;
    float acc[8][8] = {};
    for (int k0 = 0; k0 < DLb; k0 += 16) {
        #pragma unroll
        for (int i = 0; i < 2; i++) {
            int L = i * 256 + tid;
            int r = L >> 2, kq = (L & 3) * 4;
            float4 a4 = *(const float4*)&A[(size_t)(row0 + r) * DLb + k0 + kq];
            float4 b4 = *(const float4*)&W[(size_t)r * DLb + k0 + kq];
            As[kq + 0][r] = a4.x; As[kq + 1][r] = a4.y; As[kq + 2][r] = a4.z; As[kq + 3][r] = a4.w;
            Bs[kq + 0][r] = b4.x; Bs[kq + 1][r] = b4.y; Bs[kq + 2][r] = b4.z; Bs[kq + 3][r] = b4.w;
        }
        __syncthreads();
        #pragma unroll
        for (int kk = 0; kk < 16; kk++) {
            float4 a0 = *(const float4*)&As[kk][ty * 4];
            float4 a1 = *(const float4*)&As[kk][64 + ty * 4];
            float4 b0 = *(const float4*)&Bs[kk][tx * 4];
            float4 b1 = *(const float4*)&Bs[kk][64 + tx * 4];
            float ar[8] = {a0.x, a0.y, a0.z, a0.w, a1.x, a1.y, a1.z, a1.w};
            float bc[8] = {b0.x, b0.y, b0.z, b0.w, b1.x, b1.y, b1.z, b1.w};
            #pragma unroll
            for (int i = 0; i < 8; i++)
                #pragma unroll
                for (int j = 0; j < 8; j++)
                    acc[i][j] += ar[i] * bc[j];
        }
        __syncthreads();
    }
    int b = row0 >> 14;
    const float* rq = rqv + b * DLb;
    float4 bb0 = *(const float4*)&bias[tx * 4];
    float4 bb1 = *(const float4*)&bias[64 + tx * 4];
    float4 q0 = *(const float4*)&rq[tx * 4];
    float4 q1 = *(const float4*)&rq[64 + tx * 4];
    #pragma unroll
    for (int i = 0; i < 8; i++) {
        int rl = (i < 4) ? (ty * 4 + i) : (64 + ty * 4 + (i - 4));
        float ps = (acc[i][0] + bb0.x) * q0.x + (acc[i][1] + bb0.y) * q0.y
                 + (acc[i][2] + bb0.z) * q0.z + (acc[i][3] + bb0.w) * q0.w
                 + (acc[i][4] + bb1.x) * q1.x + (acc[i][5] + bb1.y) * q1.y
                 + (acc[i][6] + bb1.z) * q1.z + (acc[i][7] + bb1.w) * q1.w;
        redS[rl][tx] = ps;
    }
    __syncthreads();
    if (tid < 128) {
        float s = 0.0f;
        #pragma unroll
        for (int t = 0; t < 16; t++) s += redS[tid][t];
        logits[row0 + tid] = s * 0.08838834764831845f;
    }
}

// ---------------- K4e: per-token softmax + top-3 + wsel ----------------
__global__ __launch_bounds__(256) void k4e(const float* __restrict__ logits,
                                           float* __restrict__ probs,
                                           float* __restrict__ wsel)
{
    int n = blockIdx.x * 256 + threadIdx.x;
    if (n >= NN) return;
    float lg[EE];
    float4 l0 = *(const float4*)&logits[(size_t)n * EE];
    float4 l1 = *(const float4*)&logits[(size_t)n * EE + 4];
    lg[0] = l0.x; lg[1] = l0.y; lg[2] = l0.z; lg[3] = l0.w;
    lg[4] = l1.x; lg[5] = l1.y; lg[6] = l1.z; lg[7] = l1.w;
    float mx = lg[0];
    #pragma unroll
    for (int e = 1; e < EE; e++) mx = fmaxf(mx, lg[e]);
    float pr[EE];
    float se = 0.0f;
    #pragma unroll
    for (int e = 0; e < EE; e++) { pr[e] = expf(lg[e] - mx); se += pr[e]; }
    float inv = 1.0f / se;
    #pragma unroll
    for (int e = 0; e < EE; e++) pr[e] *= inv;
    float4 p0, p1;
    p0.x = pr[0]; p0.y = pr[1]; p0.z = pr[2]; p0.w = pr[3];
    p1.x = pr[4]; p1.y = pr[5]; p1.z = pr[6]; p1.w = pr[7];
    *(float4*)&probs[(size_t)n * EE] = p0;
    *(float4*)&probs[(size_t)n * EE + 4] = p1;
    bool used[EE] = {};
    int sel[KK];
    float sw = 0.0f;
    for (int t = 0; t < KK; t++) {
        int bi = 0; float bv = -1e30f;
        for (int e = 0; e < EE; e++)
            if (!used[e] && pr[e] > bv) { bv = pr[e]; bi = e; }
        used[bi] = true; sel[t] = bi; sw += pr[bi];
    }
    float invsw = 1.0f / sw;
    float w8[EE];
    #pragma unroll
    for (int e = 0; e < EE; e++) w8[e] = 0.0f;
    for (int t = 0; t < KK; t++) w8[sel[t]] = pr[sel[t]] * invsw;
    float4 w0, w1;
    w0.x = w8[0]; w0.y = w8[1]; w0.z = w8[2]; w0.w = w8[3];
    w1.x = w8[4]; w1.y = w8[5]; w1.z = w8[6]; w1.w = w8[7];
    *(float4*)&wsel[(size_t)n * EE] = w0;
    *(float4*)&wsel[(size_t)n * EE + 4] = w1;
}

// ---------------- K5pre: a_bf16[n][k] = wsel[n][k>>7] * gelu(rec(seq) - pe) ----------------
__global__ __launch_bounds__(256) void k5pre(const unsigned short* __restrict__ seqh,
                                             const unsigned short* __restrict__ seql,
                                             const float* __restrict__ pe,
                                             const float* __restrict__ wsel,
                                             unsigned short* __restrict__ abf)
{
    size_t g = ((size_t)blockIdx.x * 256 + threadIdx.x) * 8;
    int n = (int)(g >> 10), k0 = (int)(g & 1023);
    int e = k0 >> 7;
    float w = wsel[(size_t)n * EE + e];
    size_t soff = (size_t)n * SEQSTR + DLb + k0;
    ushort8 hv = *(const ushort8*)&seqh[soff];
    ushort8 lv = *(const ushort8*)&seql[soff];
    float4 p0 = *(const float4*)&pe[k0];
    float4 p1 = *(const float4*)&pe[k0 + 4];
    float pp[8] = {p0.x, p0.y, p0.z, p0.w, p1.x, p1.y, p1.z, p1.w};
    ushort8 o;
    #pragma unroll
    for (int i = 0; i < 8; i++) {
        float v = bf2f(hv[i]) + bf2f(lv[i]) - pp[i];
        o[i] = f2bf(w * gelu_exact(v));
    }
    *(ushort8*)&abf[g] = o;
}

// ---------------- K5t: wupT[m][k] = bf16(wup[k][m]) ----------------
__global__ __launch_bounds__(256) void k5t(const float* __restrict__ wup, unsigned short* __restrict__ wupT) {
    __shared__ float T[64][68];
    int tid = threadIdx.x;
    int k0 = blockIdx.x * 64, m0 = blockIdx.y * 64;
    #pragma unroll
    for (int i = 0; i < 4; i++) {
        int F = i * 256 + tid;
        int r = F >> 4, c4 = (F & 15) * 4;
        *(float4*)&T[r][c4] = *(const float4*)&wup[(size_t)(k0 + r) * DD + m0 + c4];
    }
    __syncthreads();
    #pragma unroll
    for (int i = 0; i < 2; i++) {
        int W = i * 256 + tid;
        int r = W >> 3, c8 = (W & 7) * 8;
        ushort8 o;
        #pragma unroll
        for (int j = 0; j < 8; j++) o[j] = f2bf(T[c8 + j][r]);
        *(ushort8*)&wupT[(size_t)(m0 + r) * DD + k0 + c8] = o;
    }
}

// ---------------- K5: out = a_bf16 @ wupT^T via MFMA 16x16x32 bf16 ----------------
__global__ __launch_bounds__(256) void k5_mfma(const unsigned short* __restrict__ A,
                                               const unsigned short* __restrict__ B,
                                               float* __restrict__ C)
{
    __shared__ __attribute__((aligned(16))) unsigned short As[128 * RSA];
    __shared__ __attribute__((aligned(16))) unsigned short Bs[128 * RSA];
    int tid = threadIdx.x;
    int lane = tid & 63, wave = tid >> 6;
    int wm = wave & 1, wn = wave >> 1;
    int row0 = blockIdx.y * 128, col0 = blockIdx.x * 128;
    int fr = lane & 15, fq = lane >> 4;
    f32x4 acc[4][4];
    #pragma unroll
    for (int i = 0; i < 4; i++)
        #pragma unroll
        for (int j = 0; j < 4; j++) acc[i][j] = (f32x4)0.0f;

    for (int k0 = 0; k0 < DD; k0 += 32) {
        #pragma unroll
        for (int i = 0; i < 2; i++) {
            int L = i * 256 + tid;
            int r = L >> 2, q = (L & 3) * 8;
            *(ushort8*)&As[r * RSA + q] = *(const ushort8*)&A[(size_t)(row0 + r) * DD + k0 + q];
            *(ushort8*)&Bs[r * RSA + q] = *(const ushort8*)&B[(size_t)(col0 + r) * DD + k0 + q];
        }
        __syncthreads();
        short8 af[4], bf[4];
        #pragma unroll
        for (int f = 0; f < 4; f++) {
            af[f] = *(const short8*)&As[(wm * 64 + f * 16 + fr) * RSA + fq * 8];
            bf[f] = *(const short8*)&Bs[(wn * 64 + f * 16 + fr) * RSA + fq * 8];
        }
        #pragma unroll
        for (int i = 0; i < 4; i++)
            #pragma unroll
            for (int j = 0; j < 4; j++)
                acc[i][j] = __builtin_amdgcn_mfma_f32_16x16x32_bf16(af[i], bf[j], acc[i][j], 0, 0, 0);
        __syncthreads();
    }
    #pragma unroll
    for (int i = 0; i < 4; i++) {
        #pragma unroll
        for (int j = 0; j < 4; j++) {
            int gc = col0 + wn * 64 + j * 16 + fr;
            #pragma unroll
            for (int r = 0; r < 4; r++) {
                int gr = row0 + wm * 64 + i * 16 + fq * 4 + r;
                C[(size_t)gr * DD + gc] = acc[i][j][r];
            }
        }
    }
}

// ---------------- K6: aux loss (two-stage) ----------------
__global__ __launch_bounds__(256) void k6a(const float* __restrict__ probs,
                                           const float* __restrict__ wsel,
                                           float* __restrict__ part)
{
    int tid = threadIdx.x;
    int n = blockIdx.x * 256 + tid;
    float lp[EE], lc[EE];
    #pragma unroll
    for (int e = 0; e < EE; e++) {
        lp[e] = probs[(size_t)n * EE + e];
        lc[e] = (wsel[(size_t)n * EE + e] > 0.0f) ? 1.0f : 0.0f;
    }
    __shared__ float bp[256][EE];
    __shared__ float bc[256][EE];
    #pragma unroll
    for (int e = 0; e < EE; e++) { bp[tid][e] = lp[e]; bc[tid][e] = lc[e]; }
    __syncthreads();
    for (int s = 128; s > 0; s >>= 1) {
        if (tid < s) {
            #pragma unroll
            for (int e = 0; e < EE; e++) {
                bp[tid][e] += bp[tid + s][e];
                bc[tid][e] += bc[tid + s][e];
            }
        }
        __syncthreads();
    }
    if (tid < EE) {
        part[blockIdx.x * 16 + tid] = bp[0][tid];
        part[blockIdx.x * 16 + 8 + tid] = bc[0][tid];
    }
}

__global__ __launch_bounds__(64) void k6b(const float* __restrict__ part, float* __restrict__ out_aux) {
    int tid = threadIdx.x;
    __shared__ float sums[16];
    if (tid < 16) {
        float s = 0.0f;
        for (int b = 0; b < NN / 256; b++) s += part[b * 16 + tid];
        sums[tid] = s;
    }
    __syncthreads();
    if (tid == 0) {
        float a = 0.0f;
        for (int e = 0; e < EE; e++) a += (sums[e] / NN) * (sums[8 + e] / NN);
        out_aux[0] = EE * a;
    }
}

extern "C" void kernel_launch(void* const* d_in, const int* in_sizes, int n_in,
                              void* d_out, int out_size, void* d_ws, size_t ws_size,
                              hipStream_t stream) {
    const float* x     = (const float*)d_in[0];
    const float* wdown = (const float*)d_in[1];
    const float* pe    = (const float*)d_in[2];
    const float* gpw   = (const float*)d_in[3];
    const float* gpb   = (const float*)d_in[4];
    const float* aiw   = (const float*)d_in[5];
    const float* aib   = (const float*)d_in[6];
    const float* aow   = (const float*)d_in[7];
    const float* aob   = (const float*)d_in[8];
    const float* nw    = (const float*)d_in[9];
    const float* nb    = (const float*)d_in[10];
    const float* rq1w  = (const float*)d_in[11];
    const float* rq1b  = (const float*)d_in[12];
    const float* rqlnw = (const float*)d_in[13];
    const float* rqlnb = (const float*)d_in[14];
    const float* rq2w  = (const float*)d_in[15];
    const float* rq2b  = (const float*)d_in[16];
    const float* rkw   = (const float*)d_in[17];
    const float* rkb   = (const float*)d_in[18];
    const float* wup   = (const float*)d_in[19];

    float* out = (float*)d_out;

    // workspace layout
    unsigned short* seqh = (unsigned short*)d_ws;                    // NN*SEQSTR us
    unsigned short* seql = seqh + (size_t)NN * SEQSTR;               // NN*SEQSTR us
    float* xregion = (float*)(seql + (size_t)NN * SEQSTR);           // NN*DD floats
    unsigned short* xh = (unsigned short*)xregion;                   // NN*DD us
    unsigned short* xl = xh + (size_t)NN * DD;                       // NN*DD us
    float* o = xregion;                                              // alias (xh/xl dead after k3s)
    unsigned short* abf = (unsigned short*)xregion;                  // alias (o dead after k4c)
    float* region = xregion + (size_t)NN * DD;                       // 8.39M floats
    float* qkvbuf = region;
    float* s2     = region;                                          // alias (qkv dead after k4b loop)
    float* probs  = region + (size_t)65536 * 128;
    float* wsel   = probs + (size_t)NN * EE;
    float* logits = wsel + (size_t)NN * EE;
    float* partial= logits + (size_t)NN * EE;
    float* mean_x = partial + (size_t)BB * NCH * DD;
    float* gctx   = mean_x + (size_t)BB * DD;
    float* rqv    = gctx + (size_t)BB * DLb;
    float* k6part = rqv + (size_t)BB * DLb;                          // 512 floats
    unsigned short* wupT = (unsigned short*)(k6part + 512);          // 1M us
    unsigned short* wdh  = wupT + (size_t)DD * DD;                   // 1M us
    unsigned short* wdl  = wdh + (size_t)DD * DD;                    // 1M us
    unsigned short* aiwh = wdl + (size_t)DD * DD;                    // 48K us
    unsigned short* aiwl = aiwh + (size_t)384 * DLb;                 // 48K us

    // pre-split passes
    hipLaunchKernelGGL(ksplit, dim3(NN * DD / 8 / 256), dim3(256), 0, stream, x, xh, xl, NN * DD / 8);
    hipLaunchKernelGGL(ksplit, dim3(DD * DD / 8 / 256), dim3(256), 0, stream, wdown, wdh, wdl, DD * DD / 8);
    hipLaunchKernelGGL(ksplit, dim3(384 * DLb / 8 / 256), dim3(256), 0, stream, aiw, aiwh, aiwl, 384 * DLb / 8);

    hipLaunchKernelGGL(k1a, dim3(DD / 256, BB, NCH), dim3(256), 0, stream, x, partial);
    hipLaunchKernelGGL(k1b, dim3(DD / 256, BB), dim3(256), 0, stream, partial, mean_x);
    hipLaunchKernelGGL(k2_batch, dim3(BB), dim3(DLb), 0, stream,
                       mean_x, gpw, gpb, rq1w, rq1b, rqlnw, rqlnb, rq2w, rq2b, gctx, rqv);
    hipLaunchKernelGGL(k2b, dim3(NN * DLb / 256), dim3(256), 0, stream, gctx, seqh, seql);
    hipLaunchKernelGGL(k3s, dim3((EE * DLb) / 128, NN / 128), dim3(256), 0, stream,
                       xh, xl, wdh, wdl, pe, seqh, seql);
    for (int s = 0; s < NSLICE; s++) {
        hipLaunchKernelGGL(k4as, dim3(3, TSL * NPOS / 128), dim3(256), 0, stream,
                           seqh + (size_t)s * TSL * SEQSTR, seql + (size_t)s * TSL * SEQSTR,
                           aiwh, aiwl, aib, qkvbuf);
        hipLaunchKernelGGL(k4b, dim3(TSL), dim3(256), 0, stream, qkvbuf, o, s * TSL);
    }
    hipLaunchKernelGGL(k4c, dim3(1, NN * EE / 128), dim3(256), 0, stream,
                       o, aow, aob, seqh, seql, nw, nb, s2);
    hipLaunchKernelGGL(k4d, dim3(1, NN * EE / 128), dim3(256), 0, stream,
                       s2, rkw, rkb, rqv, logits);
    hipLaunchKernelGGL(k4e, dim3(NN / 256), dim3(256), 0, stream, logits, probs, wsel);
    hipLaunchKernelGGL(k5t, dim3(DD / 64, DD / 64), dim3(256), 0, stream, wup, wupT);
    hipLaunchKernelGGL(k5pre, dim3(NN * DD / (256 * 8)), dim3(256), 0, stream, seqh, seql, pe, wsel, abf);
    hipLaunchKernelGGL(k5_mfma, dim3(DD / 128, NN / 128), dim3(256), 0, stream, abf, wupT, out);
    hipLaunchKernelGGL(k6a, dim3(NN / 256), dim3(256), 0, stream, probs, wsel, k6part);
    hipLaunchKernelGGL(k6b, dim3(1), dim3(64), 0, stream, k6part, out + (size_t)NN * DD);
}

// Round 6
// 410.078 us; speedup vs baseline: 1.1025x; 1.1025x over previous
//
#include <hip/hip_runtime.h>
#include <hip/hip_bf16.h>
#include <math.h>

#define BB 4
#define TT 2048
#define DD 1024
#define DLb 128
#define EE 8
#define HH 4
#define KK 3
#define HDh 32
#define NN (BB*TT)
#define NPOS 9
#define NCH 16
#define CHL (TT/NCH)
#define SEQSTR (NPOS*DLb)   // 1152
#define NSLICE 4
#define TSL (NN/NSLICE)     // 2048 tokens per slice

typedef __attribute__((ext_vector_type(8))) short short8;
typedef __attribute__((ext_vector_type(4))) float f32x4;
typedef __attribute__((ext_vector_type(8))) unsigned short ushort8;
typedef __attribute__((ext_vector_type(4))) unsigned short ushort4v;

// async global->LDS DMA, 16B per lane; LDS dest = wave-uniform base + lane*16
#define GLL(gptr, lptr) \
    __builtin_amdgcn_global_load_lds((const __attribute__((address_space(1))) unsigned int*)(gptr), \
                                     (__attribute__((address_space(3))) unsigned int*)(lptr), 16, 0, 0)

__device__ __forceinline__ float gelu_exact(float v) {
    return 0.5f * v * (1.0f + erff(v * 0.70710678118654752440f));
}

__device__ __forceinline__ unsigned short f2bf(float x) {
    __hip_bfloat16 h = __float2bfloat16(x);
    return *reinterpret_cast<unsigned short*>(&h);
}

__device__ __forceinline__ float bf2f(unsigned short u) {
    return __uint_as_float(((unsigned int)u) << 16);
}

__device__ __forceinline__ float4 rec4(const unsigned short* h, const unsigned short* l) {
    ushort4v hv = *(const ushort4v*)h;
    ushort4v lv = *(const ushort4v*)l;
    float4 r;
    r.x = bf2f(hv[0]) + bf2f(lv[0]);
    r.y = bf2f(hv[1]) + bf2f(lv[1]);
    r.z = bf2f(hv[2]) + bf2f(lv[2]);
    r.w = bf2f(hv[3]) + bf2f(lv[3]);
    return r;
}

// stage a 128-row x 32-col bf16 panel (8 KB) from row-major global (row stride L)
// into unpadded LDS [128][32], via 2 global_load_lds issues per thread.
__device__ __forceinline__ void stage_panel(const unsigned short* __restrict__ G,
                                            size_t rowBase, int L, int k0,
                                            unsigned short* lds, int tid)
{
    int r = tid >> 2, c8 = (tid & 3) * 8;
    int wave = tid >> 6;
    GLL(&G[(rowBase + r) * (size_t)L + k0 + c8], lds + wave * 512);
    GLL(&G[(rowBase + 64 + r) * (size_t)L + k0 + c8], lds + 2048 + wave * 512);
}

// ---------------- K0: generic fp32 -> (hi,lo) bf16 split ----------------
__global__ __launch_bounds__(256) void ksplit(const float* __restrict__ src,
                                              unsigned short* __restrict__ h,
                                              unsigned short* __restrict__ l, int n8)
{
    int i = blockIdx.x * 256 + threadIdx.x;
    if (i >= n8) return;
    size_t g = (size_t)i * 8;
    float4 a = *(const float4*)&src[g];
    float4 b = *(const float4*)&src[g + 4];
    float vv[8] = {a.x, a.y, a.z, a.w, b.x, b.y, b.z, b.w};
    ushort8 ho, lo;
    #pragma unroll
    for (int j = 0; j < 8; j++) {
        unsigned short hh = f2bf(vv[j]);
        float hf = bf2f(hh);
        ho[j] = hh;
        lo[j] = f2bf(vv[j] - hf);
    }
    *(ushort8*)&h[g] = ho;
    *(ushort8*)&l[g] = lo;
}

// ---------------- K1: per-batch column mean of x ----------------
__global__ __launch_bounds__(256) void k1a(const float* __restrict__ x, float* __restrict__ partial) {
    int d = blockIdx.x * 256 + threadIdx.x;
    int b = blockIdx.y, c = blockIdx.z;
    const float* xp = x + ((size_t)b * TT + (size_t)c * CHL) * DD + d;
    float s = 0.0f;
    for (int t = 0; t < CHL; t++) s += xp[(size_t)t * DD];
    partial[(b * NCH + c) * DD + d] = s;
}

__global__ __launch_bounds__(256) void k1b(const float* __restrict__ partial, float* __restrict__ mean_x) {
    int d = blockIdx.x * 256 + threadIdx.x;
    int b = blockIdx.y;
    float s = 0.0f;
    for (int c = 0; c < NCH; c++) s += partial[(b * NCH + c) * DD + d];
    mean_x[b * DD + d] = s * (1.0f / TT);
}

// ---------------- K2: per-batch gctx + rq chain + router u-vector ----------------
__global__ __launch_bounds__(128) void k2_batch(
    const float* __restrict__ mean_x,
    const float* __restrict__ gpw, const float* __restrict__ gpb,
    const float* __restrict__ rq1w, const float* __restrict__ rq1b,
    const float* __restrict__ lnw, const float* __restrict__ lnb,
    const float* __restrict__ rq2w, const float* __restrict__ rq2b,
    const float* __restrict__ rkw, const float* __restrict__ rkb,
    float* __restrict__ gctx, float* __restrict__ uv, float* __restrict__ c0v)
{
    int b = blockIdx.x, d = threadIdx.x;
    __shared__ __attribute__((aligned(16))) float g[DLb];
    __shared__ __attribute__((aligned(16))) float t1[DLb];
    __shared__ __attribute__((aligned(16))) float act[DLb];
    __shared__ __attribute__((aligned(16))) float rqs[DLb];
    __shared__ float red[2];
    {
        const float4* wrow = (const float4*)(gpw + (size_t)d * DD);
        const float4* mx4  = (const float4*)(mean_x + (size_t)b * DD);
        float s = gpb[d];
        for (int k = 0; k < DD / 4; k++) {
            float4 w = wrow[k], m = mx4[k];
            s += w.x * m.x + w.y * m.y + w.z * m.z + w.w * m.w;
        }
        g[d] = s;
        gctx[b * DLb + d] = s;
    }
    __syncthreads();
    {
        float s = rq1b[d];
        for (int k = 0; k < DLb; k++) s += g[k] * rq1w[d * DLb + k];
        t1[d] = s;
    }
    __syncthreads();
    if (d == 0) {
        float m = 0.0f;
        for (int i = 0; i < DLb; i++) m += t1[i];
        m *= (1.0f / DLb);
        float v = 0.0f;
        for (int i = 0; i < DLb; i++) { float df = t1[i] - m; v += df * df; }
        v *= (1.0f / DLb);
        red[0] = m; red[1] = 1.0f / sqrtf(v + 1e-5f);
    }
    __syncthreads();
    {
        float xn = (t1[d] - red[0]) * red[1] * lnw[d] + lnb[d];
        act[d] = gelu_exact(xn);
    }
    __syncthreads();
    {
        float s = rq2b[d];
        for (int k = 0; k < DLb; k++) s += act[k] * rq2w[d * DLb + k];
        rqs[d] = s;
    }
    __syncthreads();
    // u[d] = sum_k rq[k] * rkw[k][d]  (rkw row-major [k][d] -> rkw[k*DLb + d])
    {
        float u = 0.0f;
        for (int k = 0; k < DLb; k++) u += rqs[k] * rkw[(size_t)k * DLb + d];
        uv[b * DLb + d] = u;
    }
    if (d == 0) {
        float c0 = 0.0f;
        for (int k = 0; k < DLb; k++) c0 += rqs[k] * rkb[k];
        c0v[b] = c0;
    }
}

// ---------------- K2b: fill seq position 0 with gctx (split) ----------------
__global__ __launch_bounds__(256) void k2b(const float* __restrict__ gctx,
                                           unsigned short* __restrict__ seqh,
                                           unsigned short* __restrict__ seql) {
    int i = blockIdx.x * 256 + threadIdx.x;
    int n = i >> 7, d = i & 127;
    float v = gctx[(n >> 11) * DLb + d];
    unsigned short h = f2bf(v);
    seqh[(size_t)n * SEQSTR + d] = h;
    seql[(size_t)n * SEQSTR + d] = f2bf(v - bf2f(h));
}

// ---------------- K3s: seq[:,1:,:] = x @ w_down^T + pe (split-bf16 MFMA, GLL staging) ----------------
__global__ __launch_bounds__(256) void k3s(const unsigned short* __restrict__ XH,
                                           const unsigned short* __restrict__ XL,
                                           const unsigned short* __restrict__ WH,
                                           const unsigned short* __restrict__ WL,
                                           const float* __restrict__ pe,
                                           unsigned short* __restrict__ seqh,
                                           unsigned short* __restrict__ seql)
{
    __shared__ __attribute__((aligned(16))) unsigned short Ah[128 * 32];
    __shared__ __attribute__((aligned(16))) unsigned short Al[128 * 32];
    __shared__ __attribute__((aligned(16))) unsigned short Bh[128 * 32];
    __shared__ __attribute__((aligned(16))) unsigned short Bl[128 * 32];
    int tid = threadIdx.x;
    int lane = tid & 63, wave = tid >> 6;
    int wm = wave & 1, wn = wave >> 1;
    int row0 = blockIdx.y * 128, col0 = blockIdx.x * 128;
    int fr = lane & 15, fq = lane >> 4;
    f32x4 acc[4][4];
    #pragma unroll
    for (int i = 0; i < 4; i++)
        #pragma unroll
        for (int j = 0; j < 4; j++) acc[i][j] = (f32x4)0.0f;

    for (int k0 = 0; k0 < DD; k0 += 32) {
        stage_panel(XH, row0, DD, k0, Ah, tid);
        stage_panel(XL, row0, DD, k0, Al, tid);
        stage_panel(WH, col0, DD, k0, Bh, tid);
        stage_panel(WL, col0, DD, k0, Bl, tid);
        __syncthreads();
        short8 ah[4], al4[4], bh[4], bl4[4];
        #pragma unroll
        for (int f = 0; f < 4; f++) {
            int ra = (wm * 64 + f * 16 + fr) * 32 + fq * 8;
            int rb = (wn * 64 + f * 16 + fr) * 32 + fq * 8;
            ah[f]  = *(const short8*)&Ah[ra];
            al4[f] = *(const short8*)&Al[ra];
            bh[f]  = *(const short8*)&Bh[rb];
            bl4[f] = *(const short8*)&Bl[rb];
        }
        #pragma unroll
        for (int i = 0; i < 4; i++)
            #pragma unroll
            for (int j = 0; j < 4; j++) {
                acc[i][j] = __builtin_amdgcn_mfma_f32_16x16x32_bf16(ah[i],  bh[j],  acc[i][j], 0, 0, 0);
                acc[i][j] = __builtin_amdgcn_mfma_f32_16x16x32_bf16(ah[i],  bl4[j], acc[i][j], 0, 0, 0);
                acc[i][j] = __builtin_amdgcn_mfma_f32_16x16x32_bf16(al4[i], bh[j],  acc[i][j], 0, 0, 0);
            }
        __syncthreads();
    }
    #pragma unroll
    for (int j = 0; j < 4; j++) {
        int gc = col0 + wn * 64 + j * 16 + fr;
        float pv = pe[gc];
        #pragma unroll
        for (int i = 0; i < 4; i++) {
            #pragma unroll
            for (int r = 0; r < 4; r++) {
                int gr = row0 + wm * 64 + i * 16 + fq * 4 + r;
                float v = acc[i][j][r] + pv;
                unsigned short h = f2bf(v);
                size_t idx = (size_t)gr * SEQSTR + DLb + gc;
                seqh[idx] = h;
                seql[idx] = f2bf(v - bf2f(h));
            }
        }
    }
}

// ---------------- K4as: qkv slice GEMM (split-bf16 MFMA, GLL staging) ----------------
__global__ __launch_bounds__(256) void k4as(const unsigned short* __restrict__ AHp,
                                            const unsigned short* __restrict__ ALp,
                                            const unsigned short* __restrict__ WHp,
                                            const unsigned short* __restrict__ WLp,
                                            const float* __restrict__ bias,
                                            float* __restrict__ C)
{
    __shared__ __attribute__((aligned(16))) unsigned short Ah[128 * 32];
    __shared__ __attribute__((aligned(16))) unsigned short Al[128 * 32];
    __shared__ __attribute__((aligned(16))) unsigned short Bh[128 * 32];
    __shared__ __attribute__((aligned(16))) unsigned short Bl[128 * 32];
    int tid = threadIdx.x;
    int lane = tid & 63, wave = tid >> 6;
    int wm = wave & 1, wn = wave >> 1;
    int row0 = blockIdx.y * 128, col0 = blockIdx.x * 128;
    int fr = lane & 15, fq = lane >> 4;
    f32x4 acc[4][4];
    #pragma unroll
    for (int i = 0; i < 4; i++)
        #pragma unroll
        for (int j = 0; j < 4; j++) acc[i][j] = (f32x4)0.0f;

    for (int k0 = 0; k0 < DLb; k0 += 32) {
        stage_panel(AHp, row0, DLb, k0, Ah, tid);
        stage_panel(ALp, row0, DLb, k0, Al, tid);
        stage_panel(WHp, col0, DLb, k0, Bh, tid);
        stage_panel(WLp, col0, DLb, k0, Bl, tid);
        __syncthreads();
        short8 ah[4], al4[4], bh[4], bl4[4];
        #pragma unroll
        for (int f = 0; f < 4; f++) {
            int ra = (wm * 64 + f * 16 + fr) * 32 + fq * 8;
            int rb = (wn * 64 + f * 16 + fr) * 32 + fq * 8;
            ah[f]  = *(const short8*)&Ah[ra];
            al4[f] = *(const short8*)&Al[ra];
            bh[f]  = *(const short8*)&Bh[rb];
            bl4[f] = *(const short8*)&Bl[rb];
        }
        #pragma unroll
        for (int i = 0; i < 4; i++)
            #pragma unroll
            for (int j = 0; j < 4; j++) {
                acc[i][j] = __builtin_amdgcn_mfma_f32_16x16x32_bf16(ah[i],  bh[j],  acc[i][j], 0, 0, 0);
                acc[i][j] = __builtin_amdgcn_mfma_f32_16x16x32_bf16(ah[i],  bl4[j], acc[i][j], 0, 0, 0);
                acc[i][j] = __builtin_amdgcn_mfma_f32_16x16x32_bf16(al4[i], bh[j],  acc[i][j], 0, 0, 0);
            }
        __syncthreads();
    }
    #pragma unroll
    for (int j = 0; j < 4; j++) {
        int gc = col0 + wn * 64 + j * 16 + fr;
        float bv = bias[gc];
        #pragma unroll
        for (int i = 0; i < 4; i++) {
            #pragma unroll
            for (int r = 0; r < 4; r++) {
                int gr = row0 + wm * 64 + i * 16 + fq * 4 + r;
                C[(size_t)gr * 384 + gc] = acc[i][j][r] + bv;
            }
        }
    }
}

// ---------------- K4b: per-token attention (softmax + attn@v), pos 1..8 only ----------------
__global__ __launch_bounds__(256) void k4b(const float* __restrict__ qkv,
                                           float* __restrict__ og, int n0)
{
    int nl = blockIdx.x;
    int tid = threadIdx.x;
    __shared__ __attribute__((aligned(16))) float sq[NPOS][384];
    __shared__ float attnw[HH][NPOS][12];
    {
        const float4* src = (const float4*)(qkv + (size_t)nl * NPOS * 384);
        float4* dst = (float4*)&sq[0][0];
        for (int i = tid; i < NPOS * 384 / 4; i += 256) dst[i] = src[i];
    }
    __syncthreads();
    if (tid < HH * NPOS) {
        int h = tid / NPOS, i = tid % NPOS;
        float sc[NPOS];
        float mx = -1e30f;
        for (int j = 0; j < NPOS; j++) {
            float s = 0.0f;
            for (int d2 = 0; d2 < HDh; d2++)
                s += sq[i][h * HDh + d2] * sq[j][DLb + h * HDh + d2];
            s *= 0.17677669529663687f;
            sc[j] = s;
            mx = fmaxf(mx, s);
        }
        float se = 0.0f;
        for (int j = 0; j < NPOS; j++) { sc[j] = expf(sc[j] - mx); se += sc[j]; }
        float inv = 1.0f / se;
        for (int j = 0; j < NPOS; j++) attnw[h][i][j] = sc[j] * inv;
    }
    __syncthreads();
    #pragma unroll
    for (int it = 0; it < 4; it++) {
        int idx = it * 256 + tid;
        int p = 1 + (idx >> 7), d = idx & 127, h = d >> 5;
        float s = 0.0f;
        #pragma unroll
        for (int j = 0; j < NPOS; j++) s += attnw[h][p][j] * sq[j][2 * DLb + d];
        og[((size_t)(n0 + nl) * 8 + (p - 1)) * DLb + d] = s;
    }
}

// ---------------- K4cd: logits = LN(o@aow^T + aob + residual) . u + c0 (fused, no s2/rk) ----------------
__global__ __launch_bounds__(256) void k4cd(const float* __restrict__ A,
                                            const float* __restrict__ W,
                                            const float* __restrict__ bias,
                                            const unsigned short* __restrict__ seqh,
                                            const unsigned short* __restrict__ seql,
                                            const float* __restrict__ nw,
                                            const float* __restrict__ nb,
                                            const float* __restrict__ uv,
                                            const float* __restrict__ c0v,
                                            float* __restrict__ logits)
{
    __shared__ __attribute__((aligned(16))) float As[16][132];
    __shared__ __attribute__((aligned(16))) float Bs[16][132];
    __shared__ float redS[128][17];
    __shared__ float mstat[128][2];
    int tid = threadIdx.x;
    int tx = tid & 15, ty = tid >> 4;
    int row0 = blockIdx.y * 128;
    float acc[8][8] = {};
    for (int k0 = 0; k0 < DLb; k0 += 16) {
        #pragma unroll
        for (int i = 0; i < 2; i++) {
            int L = i * 256 + tid;
            int r = L >> 2, kq = (L & 3) * 4;
            float4 a4 = *(const float4*)&A[(size_t)(row0 + r) * DLb + k0 + kq];
            float4 b4 = *(const float4*)&W[(size_t)r * DLb + k0 + kq];
            As[kq + 0][r] = a4.x; As[kq + 1][r] = a4.y; As[kq + 2][r] = a4.z; As[kq + 3][r] = a4.w;
            Bs[kq + 0][r] = b4.x; Bs[kq + 1][r] = b4.y; Bs[kq + 2][r] = b4.z; Bs[kq + 3][r] = b4.w;
        }
        __syncthreads();
        #pragma unroll
        for (int kk = 0; kk < 16; kk++) {
            float4 a0 = *(const float4*)&As[kk][ty * 4];
            float4 a1 = *(const float4*)&As[kk][64 + ty * 4];
            float4 b0 = *(const float4*)&Bs[kk][tx * 4];
            float4 b1 = *(const float4*)&Bs[kk][64 + tx * 4];
            float ar[8] = {a0.x, a0.y, a0.z, a0.w, a1.x, a1.y, a1.z, a1.w};
            float bc[8] = {b0.x, b0.y, b0.z, b0.w, b1.x, b1.y, b1.z, b1.w};
            #pragma unroll
            for (int i = 0; i < 8; i++)
                #pragma unroll
                for (int j = 0; j < 8; j++)
                    acc[i][j] += ar[i] * bc[j];
        }
        __syncthreads();
    }
    int b = row0 >> 14;
    float4 bb0 = *(const float4*)&bias[tx * 4];
    float4 bb1 = *(const float4*)&bias[64 + tx * 4];
    // bias + residual; row-sum partials for mean
    #pragma unroll
    for (int i = 0; i < 8; i++) {
        int rl = (i < 4) ? (ty * 4 + i) : (64 + ty * 4 + (i - 4));
        int m = row0 + rl;
        size_t roff = (size_t)(m >> 3) * SEQSTR + (size_t)((m & 7) + 1) * DLb;
        float4 r0 = rec4(&seqh[roff + tx * 4], &seql[roff + tx * 4]);
        float4 r1 = rec4(&seqh[roff + 64 + tx * 4], &seql[roff + 64 + tx * 4]);
        acc[i][0] += bb0.x + r0.x; acc[i][1] += bb0.y + r0.y;
        acc[i][2] += bb0.z + r0.z; acc[i][3] += bb0.w + r0.w;
        acc[i][4] += bb1.x + r1.x; acc[i][5] += bb1.y + r1.y;
        acc[i][6] += bb1.z + r1.z; acc[i][7] += bb1.w + r1.w;
        float ps = 0.0f;
        #pragma unroll
        for (int j = 0; j < 8; j++) ps += acc[i][j];
        redS[rl][tx] = ps;
    }
    __syncthreads();
    if (tid < 128) {
        float s = 0.0f;
        #pragma unroll
        for (int t = 0; t < 16; t++) s += redS[tid][t];
        mstat[tid][0] = s * (1.0f / DLb);
    }
    __syncthreads();
    #pragma unroll
    for (int i = 0; i < 8; i++) {
        int rl = (i < 4) ? (ty * 4 + i) : (64 + ty * 4 + (i - 4));
        float m = mstat[rl][0];
        float pv = 0.0f;
        #pragma unroll
        for (int j = 0; j < 8; j++) { float df = acc[i][j] - m; pv += df * df; }
        redS[rl][tx] = pv;
    }
    __syncthreads();
    if (tid < 128) {
        float s = 0.0f;
        #pragma unroll
        for (int t = 0; t < 16; t++) s += redS[tid][t];
        mstat[tid][1] = 1.0f / sqrtf(s * (1.0f / DLb) + 1e-5f);
    }
    __syncthreads();
    const float* u = uv + b * DLb;
    float4 nw0 = *(const float4*)&nw[tx * 4];
    float4 nw1 = *(const float4*)&nw[64 + tx * 4];
    float4 nb0 = *(const float4*)&nb[tx * 4];
    float4 nb1 = *(const float4*)&nb[64 + tx * 4];
    float4 u0 = *(const float4*)&u[tx * 4];
    float4 u1 = *(const float4*)&u[64 + tx * 4];
    #pragma unroll
    for (int i = 0; i < 8; i++) {
        int rl = (i < 4) ? (ty * 4 + i) : (64 + ty * 4 + (i - 4));
        float m = mstat[rl][0], istd = mstat[rl][1];
        float ps;
        ps  = ((acc[i][0] - m) * istd * nw0.x + nb0.x) * u0.x;
        ps += ((acc[i][1] - m) * istd * nw0.y + nb0.y) * u0.y;
        ps += ((acc[i][2] - m) * istd * nw0.z + nb0.z) * u0.z;
        ps += ((acc[i][3] - m) * istd * nw0.w + nb0.w) * u0.w;
        ps += ((acc[i][4] - m) * istd * nw1.x + nb1.x) * u1.x;
        ps += ((acc[i][5] - m) * istd * nw1.y + nb1.y) * u1.y;
        ps += ((acc[i][6] - m) * istd * nw1.z + nb1.z) * u1.z;
        ps += ((acc[i][7] - m) * istd * nw1.w + nb1.w) * u1.w;
        redS[rl][tx] = ps;
    }
    __syncthreads();
    if (tid < 128) {
        float s = 0.0f;
        #pragma unroll
        for (int t = 0; t < 16; t++) s += redS[tid][t];
        logits[row0 + tid] = (s + c0v[b]) * 0.08838834764831845f;   // 1/sqrt(128)
    }
}

// ---------------- K4e: per-token softmax + top-3 + wsel ----------------
__global__ __launch_bounds__(256) void k4e(const float* __restrict__ logits,
                                           float* __restrict__ probs,
                                           float* __restrict__ wsel)
{
    int n = blockIdx.x * 256 + threadIdx.x;
    if (n >= NN) return;
    float lg[EE];
    float4 l0 = *(const float4*)&logits[(size_t)n * EE];
    float4 l1 = *(const float4*)&logits[(size_t)n * EE + 4];
    lg[0] = l0.x; lg[1] = l0.y; lg[2] = l0.z; lg[3] = l0.w;
    lg[4] = l1.x; lg[5] = l1.y; lg[6] = l1.z; lg[7] = l1.w;
    float mx = lg[0];
    #pragma unroll
    for (int e = 1; e < EE; e++) mx = fmaxf(mx, lg[e]);
    float pr[EE];
    float se = 0.0f;
    #pragma unroll
    for (int e = 0; e < EE; e++) { pr[e] = expf(lg[e] - mx); se += pr[e]; }
    float inv = 1.0f / se;
    #pragma unroll
    for (int e = 0; e < EE; e++) pr[e] *= inv;
    float4 p0, p1;
    p0.x = pr[0]; p0.y = pr[1]; p0.z = pr[2]; p0.w = pr[3];
    p1.x = pr[4]; p1.y = pr[5]; p1.z = pr[6]; p1.w = pr[7];
    *(float4*)&probs[(size_t)n * EE] = p0;
    *(float4*)&probs[(size_t)n * EE + 4] = p1;
    bool used[EE] = {};
    int sel[KK];
    float sw = 0.0f;
    for (int t = 0; t < KK; t++) {
        int bi = 0; float bv = -1e30f;
        for (int e = 0; e < EE; e++)
            if (!used[e] && pr[e] > bv) { bv = pr[e]; bi = e; }
        used[bi] = true; sel[t] = bi; sw += pr[bi];
    }
    float invsw = 1.0f / sw;
    float w8[EE];
    #pragma unroll
    for (int e = 0; e < EE; e++) w8[e] = 0.0f;
    for (int t = 0; t < KK; t++) w8[sel[t]] = pr[sel[t]] * invsw;
    float4 w0, w1;
    w0.x = w8[0]; w0.y = w8[1]; w0.z = w8[2]; w0.w = w8[3];
    w1.x = w8[4]; w1.y = w8[5]; w1.z = w8[6]; w1.w = w8[7];
    *(float4*)&wsel[(size_t)n * EE] = w0;
    *(float4*)&wsel[(size_t)n * EE + 4] = w1;
}

// ---------------- K5pre: a_bf16[n][k] = wsel[n][k>>7] * gelu(rec(seq) - pe) ----------------
__global__ __launch_bounds__(256) void k5pre(const unsigned short* __restrict__ seqh,
                                             const unsigned short* __restrict__ seql,
                                             const float* __restrict__ pe,
                                             const float* __restrict__ wsel,
                                             unsigned short* __restrict__ abf)
{
    size_t g = ((size_t)blockIdx.x * 256 + threadIdx.x) * 8;
    int n = (int)(g >> 10), k0 = (int)(g & 1023);
    int e = k0 >> 7;
    float w = wsel[(size_t)n * EE + e];
    size_t soff = (size_t)n * SEQSTR + DLb + k0;
    ushort8 hv = *(const ushort8*)&seqh[soff];
    ushort8 lv = *(const ushort8*)&seql[soff];
    float4 p0 = *(const float4*)&pe[k0];
    float4 p1 = *(const float4*)&pe[k0 + 4];
    float pp[8] = {p0.x, p0.y, p0.z, p0.w, p1.x, p1.y, p1.z, p1.w};
    ushort8 o;
    #pragma unroll
    for (int i = 0; i < 8; i++) {
        float v = bf2f(hv[i]) + bf2f(lv[i]) - pp[i];
        o[i] = f2bf(w * gelu_exact(v));
    }
    *(ushort8*)&abf[g] = o;
}

// ---------------- K5t: wupT[m][k] = bf16(wup[k][m]) ----------------
__global__ __launch_bounds__(256) void k5t(const float* __restrict__ wup, unsigned short* __restrict__ wupT) {
    __shared__ float T[64][68];
    int tid = threadIdx.x;
    int k0 = blockIdx.x * 64, m0 = blockIdx.y * 64;
    #pragma unroll
    for (int i = 0; i < 4; i++) {
        int F = i * 256 + tid;
        int r = F >> 4, c4 = (F & 15) * 4;
        *(float4*)&T[r][c4] = *(const float4*)&wup[(size_t)(k0 + r) * DD + m0 + c4];
    }
    __syncthreads();
    #pragma unroll
    for (int i = 0; i < 2; i++) {
        int W = i * 256 + tid;
        int r = W >> 3, c8 = (W & 7) * 8;
        ushort8 o;
        #pragma unroll
        for (int j = 0; j < 8; j++) o[j] = f2bf(T[c8 + j][r]);
        *(ushort8*)&wupT[(size_t)(m0 + r) * DD + k0 + c8] = o;
    }
}

// ---------------- K5: out = a_bf16 @ wupT^T via MFMA 16x16x32 bf16 (GLL staging) ----------------
__global__ __launch_bounds__(256) void k5_mfma(const unsigned short* __restrict__ A,
                                               const unsigned short* __restrict__ B,
                                               float* __restrict__ C)
{
    __shared__ __attribute__((aligned(16))) unsigned short As[128 * 32];
    __shared__ __attribute__((aligned(16))) unsigned short Bs[128 * 32];
    int tid = threadIdx.x;
    int lane = tid & 63, wave = tid >> 6;
    int wm = wave & 1, wn = wave >> 1;
    int row0 = blockIdx.y * 128, col0 = blockIdx.x * 128;
    int fr = lane & 15, fq = lane >> 4;
    f32x4 acc[4][4];
    #pragma unroll
    for (int i = 0; i < 4; i++)
        #pragma unroll
        for (int j = 0; j < 4; j++) acc[i][j] = (f32x4)0.0f;

    for (int k0 = 0; k0 < DD; k0 += 32) {
        stage_panel(A, row0, DD, k0, As, tid);
        stage_panel(B, col0, DD, k0, Bs, tid);
        __syncthreads();
        short8 af[4], bf[4];
        #pragma unroll
        for (int f = 0; f < 4; f++) {
            af[f] = *(const short8*)&As[(wm * 64 + f * 16 + fr) * 32 + fq * 8];
            bf[f] = *(const short8*)&Bs[(wn * 64 + f * 16 + fr) * 32 + fq * 8];
        }
        #pragma unroll
        for (int i = 0; i < 4; i++)
            #pragma unroll
            for (int j = 0; j < 4; j++)
                acc[i][j] = __builtin_amdgcn_mfma_f32_16x16x32_bf16(af[i], bf[j], acc[i][j], 0, 0, 0);
        __syncthreads();
    }
    #pragma unroll
    for (int i = 0; i < 4; i++) {
        #pragma unroll
        for (int j = 0; j < 4; j++) {
            int gc = col0 + wn * 64 + j * 16 + fr;
            #pragma unroll
            for (int r = 0; r < 4; r++) {
                int gr = row0 + wm * 64 + i * 16 + fq * 4 + r;
                C[(size_t)gr * DD + gc] = acc[i][j][r];
            }
        }
    }
}

// ---------------- K6: aux loss (two-stage) ----------------
__global__ __launch_bounds__(256) void k6a(const float* __restrict__ probs,
                                           const float* __restrict__ wsel,
                                           float* __restrict__ part)
{
    int tid = threadIdx.x;
    int n = blockIdx.x * 256 + tid;
    float lp[EE], lc[EE];
    #pragma unroll
    for (int e = 0; e < EE; e++) {
        lp[e] = probs[(size_t)n * EE + e];
        lc[e] = (wsel[(size_t)n * EE + e] > 0.0f) ? 1.0f : 0.0f;
    }
    __shared__ float bp[256][EE];
    __shared__ float bc[256][EE];
    #pragma unroll
    for (int e = 0; e < EE; e++) { bp[tid][e] = lp[e]; bc[tid][e] = lc[e]; }
    __syncthreads();
    for (int s = 128; s > 0; s >>= 1) {
        if (tid < s) {
            #pragma unroll
            for (int e = 0; e < EE; e++) {
                bp[tid][e] += bp[tid + s][e];
                bc[tid][e] += bc[tid + s][e];
            }
        }
        __syncthreads();
    }
    if (tid < EE) {
        part[blockIdx.x * 16 + tid] = bp[0][tid];
        part[blockIdx.x * 16 + 8 + tid] = bc[0][tid];
    }
}

__global__ __launch_bounds__(64) void k6b(const float* __restrict__ part, float* __restrict__ out_aux) {
    int tid = threadIdx.x;
    __shared__ float sums[16];
    if (tid < 16) {
        float s = 0.0f;
        for (int b = 0; b < NN / 256; b++) s += part[b * 16 + tid];
        sums[tid] = s;
    }
    __syncthreads();
    if (tid == 0) {
        float a = 0.0f;
        for (int e = 0; e < EE; e++) a += (sums[e] / NN) * (sums[8 + e] / NN);
        out_aux[0] = EE * a;
    }
}

extern "C" void kernel_launch(void* const* d_in, const int* in_sizes, int n_in,
                              void* d_out, int out_size, void* d_ws, size_t ws_size,
                              hipStream_t stream) {
    const float* x     = (const float*)d_in[0];
    const float* wdown = (const float*)d_in[1];
    const float* pe    = (const float*)d_in[2];
    const float* gpw   = (const float*)d_in[3];
    const float* gpb   = (const float*)d_in[4];
    const float* aiw   = (const float*)d_in[5];
    const float* aib   = (const float*)d_in[6];
    const float* aow   = (const float*)d_in[7];
    const float* aob   = (const float*)d_in[8];
    const float* nw    = (const float*)d_in[9];
    const float* nb    = (const float*)d_in[10];
    const float* rq1w  = (const float*)d_in[11];
    const float* rq1b  = (const float*)d_in[12];
    const float* rqlnw = (const float*)d_in[13];
    const float* rqlnb = (const float*)d_in[14];
    const float* rq2w  = (const float*)d_in[15];
    const float* rq2b  = (const float*)d_in[16];
    const float* rkw   = (const float*)d_in[17];
    const float* rkb   = (const float*)d_in[18];
    const float* wup   = (const float*)d_in[19];

    float* out = (float*)d_out;

    // workspace layout
    unsigned short* seqh = (unsigned short*)d_ws;                    // NN*SEQSTR us
    unsigned short* seql = seqh + (size_t)NN * SEQSTR;               // NN*SEQSTR us
    float* xregion = (float*)(seql + (size_t)NN * SEQSTR);           // NN*DD floats
    unsigned short* xh = (unsigned short*)xregion;                   // NN*DD us
    unsigned short* xl = xh + (size_t)NN * DD;                       // NN*DD us
    float* o = xregion;                                              // alias (xh/xl dead after k3s)
    unsigned short* abf = (unsigned short*)xregion;                  // alias (o dead after k4cd)
    float* region = xregion + (size_t)NN * DD;                       // 8.39M floats
    float* qkvbuf = region;                                          // 18432*384 fits
    float* probs  = region + (size_t)65536 * 128;
    float* wsel   = probs + (size_t)NN * EE;
    float* logits = wsel + (size_t)NN * EE;
    float* partial= logits + (size_t)NN * EE;
    float* mean_x = partial + (size_t)BB * NCH * DD;
    float* gctx   = mean_x + (size_t)BB * DD;
    float* uv     = gctx + (size_t)BB * DLb;                         // BB*DLb
    float* c0v    = uv + (size_t)BB * DLb;                           // BB
    float* k6part = c0v + 64;                                        // 512 floats
    unsigned short* wupT = (unsigned short*)(k6part + 512);          // 1M us
    unsigned short* wdh  = wupT + (size_t)DD * DD;                   // 1M us
    unsigned short* wdl  = wdh + (size_t)DD * DD;                    // 1M us
    unsigned short* aiwh = wdl + (size_t)DD * DD;                    // 48K us
    unsigned short* aiwl = aiwh + (size_t)384 * DLb;                 // 48K us

    // pre-split passes
    hipLaunchKernelGGL(ksplit, dim3(NN * DD / 8 / 256), dim3(256), 0, stream, x, xh, xl, NN * DD / 8);
    hipLaunchKernelGGL(ksplit, dim3(DD * DD / 8 / 256), dim3(256), 0, stream, wdown, wdh, wdl, DD * DD / 8);
    hipLaunchKernelGGL(ksplit, dim3(384 * DLb / 8 / 256), dim3(256), 0, stream, aiw, aiwh, aiwl, 384 * DLb / 8);

    hipLaunchKernelGGL(k1a, dim3(DD / 256, BB, NCH), dim3(256), 0, stream, x, partial);
    hipLaunchKernelGGL(k1b, dim3(DD / 256, BB), dim3(256), 0, stream, partial, mean_x);
    hipLaunchKernelGGL(k2_batch, dim3(BB), dim3(DLb), 0, stream,
                       mean_x, gpw, gpb, rq1w, rq1b, rqlnw, rqlnb, rq2w, rq2b, rkw, rkb,
                       gctx, uv, c0v);
    hipLaunchKernelGGL(k2b, dim3(NN * DLb / 256), dim3(256), 0, stream, gctx, seqh, seql);
    hipLaunchKernelGGL(k3s, dim3((EE * DLb) / 128, NN / 128), dim3(256), 0, stream,
                       xh, xl, wdh, wdl, pe, seqh, seql);
    for (int s = 0; s < NSLICE; s++) {
        hipLaunchKernelGGL(k4as, dim3(3, TSL * NPOS / 128), dim3(256), 0, stream,
                           seqh + (size_t)s * TSL * SEQSTR, seql + (size_t)s * TSL * SEQSTR,
                           aiwh, aiwl, aib, qkvbuf);
        hipLaunchKernelGGL(k4b, dim3(TSL), dim3(256), 0, stream, qkvbuf, o, s * TSL);
    }
    hipLaunchKernelGGL(k4cd, dim3(1, NN * EE / 128), dim3(256), 0, stream,
                       o, aow, aob, seqh, seql, nw, nb, uv, c0v, logits);
    hipLaunchKernelGGL(k4e, dim3(NN / 256), dim3(256), 0, stream, logits, probs, wsel);
    hipLaunchKernelGGL(k5t, dim3(DD / 64, DD / 64), dim3(256), 0, stream, wup, wupT);
    hipLaunchKernelGGL(k5pre, dim3(NN * DD / (256 * 8)), dim3(256), 0, stream, seqh, seql, pe, wsel, abf);
    hipLaunchKernelGGL(k5_mfma, dim3(DD / 128, NN / 128), dim3(256), 0, stream, abf, wupT, out);
    hipLaunchKernelGGL(k6a, dim3(NN / 256), dim3(256), 0, stream, probs, wsel, k6part);
    hipLaunchKernelGGL(k6b, dim3(1), dim3(64), 0, stream, k6part, out + (size_t)NN * DD);
}